// Round 17
// baseline (746.959 us; speedup 1.0000x reference)
//
#include <hip/hip_runtime.h>
#include <hip/hip_bf16.h>

// ---------------------------------------------------------------------------
// TransformerEncoder: B=2, S=2048, D=512, H=8, DH=64, DF=2048, NX=6 layers
// I/O fp32. bf16 MFMA GEMMs (templated BM; BK=64, XOR-swizzled LDS +
// pre-swizzled global_load_lds source, 2-phase dbuf, XCD swizzle).
// QKV: BM=64 grid 768 (3/CU). Wo: BM=64 splitk=1. FF1: BM=128. FF2: BM=128
// splitk=2 (K=2048 regime). Attention: 4-wave QBLK=64 grid 512 (2 blocks/CU
// for barrier overlap — R17 isolated A/B), swapped QK^T + sigma-permuted
// in-register P, exp2 softmax, defer-max. Fused weight+bias prep, fp32 LN.
// ---------------------------------------------------------------------------

typedef __attribute__((ext_vector_type(4))) float  floatx4;
typedef __attribute__((ext_vector_type(8))) short  short8;
typedef __bf16 bf16x8 __attribute__((ext_vector_type(8)));

#define SS 2048
#define DD 512
#define HH 8
#define DHH 64
#define NROWS 4096   /* B*S */
#define QS 1536      /* fused qkv row stride */

__device__ __forceinline__ float bf2f(unsigned short u) {
    union { float f; unsigned int i; } x; x.i = ((unsigned int)u) << 16; return x.f;
}
__device__ __forceinline__ unsigned short f2bf(float f) {
    union { float f; unsigned int i; } x; x.f = f;
    unsigned int lsb = (x.i >> 16) & 1u;
    x.i += 0x7fffu + lsb;
    return (unsigned short)(x.i >> 16);
}
// round-half-up for positive finite values (softmax P)
__device__ __forceinline__ unsigned short f2bf_fast(float f) {
    union { float f; unsigned int i; } x; x.f = f;
    return (unsigned short)((x.i + 0x8000u) >> 16);
}

#if __has_builtin(__builtin_amdgcn_exp2f)
#define EXP2F(x) __builtin_amdgcn_exp2f(x)
#else
#define EXP2F(x) exp2f(x)
#endif

#if __has_builtin(__builtin_amdgcn_mfma_f32_16x16x32_bf16)
__device__ __forceinline__ void mfma16x16x32(floatx4& d, short8 a, short8 b) {
    bf16x8 ab, bb;
    __builtin_memcpy(&ab, &a, 16);
    __builtin_memcpy(&bb, &b, 16);
    d = __builtin_amdgcn_mfma_f32_16x16x32_bf16(ab, bb, d, 0, 0, 0);
}
#else
__device__ __forceinline__ void mfma16x16x32(floatx4& d, short8 a, short8 b) {
    asm volatile("s_nop 1\n\t"
                 "v_mfma_f32_16x16x32_bf16 %0, %1, %2, %0\n\t"
                 "s_nop 7\n\t"
                 "s_nop 7"
                 : "+v"(d) : "v"(a), "v"(b));
}
#endif

// stage 16B/lane: g = per-lane global src, lbase = wave-uniform LDS chunk base
#if __has_builtin(__builtin_amdgcn_global_load_lds)
__device__ __forceinline__ void stage16(const ushort* g, ushort* lbase, int lane) {
    __builtin_amdgcn_global_load_lds(
        (const __attribute__((address_space(1))) unsigned int*)g,
        (__attribute__((address_space(3))) unsigned int*)lbase, 16, 0, 0);
}
#else
__device__ __forceinline__ void stage16(const ushort* g, ushort* lbase, int lane) {
    *(short8*)(lbase + lane * 8) = *(const short8*)g;
}
#endif

// ---------------------------------------------------------------------------
// All weight transposes (fp32 -> bf16, [z][R][C] -> [C][R]) + qkv bias concat
// in ONE kernel. Blocks 0..18431: transpose tiles; 18432..18437: bias concat.
// ---------------------------------------------------------------------------
__global__ __launch_bounds__(256) void prep_weights(const float* __restrict__ Wq,
                                                    const float* __restrict__ Wk,
                                                    const float* __restrict__ Wv,
                                                    const float* __restrict__ Wo,
                                                    const float* __restrict__ W1,
                                                    const float* __restrict__ W2,
                                                    const float* __restrict__ bq,
                                                    const float* __restrict__ bk,
                                                    const float* __restrict__ bv,
                                                    ushort* __restrict__ qkvT,
                                                    ushort* __restrict__ WoT,
                                                    ushort* __restrict__ W1T,
                                                    ushort* __restrict__ W2T,
                                                    float* __restrict__ qkvB) {
    __shared__ ushort t[32][33];
    int bid = blockIdx.x;
    if (bid >= 18432) {            // bias concat: one block per layer
        int z = bid - 18432;
        int idx = threadIdx.y * 32 + threadIdx.x;
        for (int i = idx; i < 512; i += 256) {
            qkvB[z * QS + i]        = bq[z * DD + i];
            qkvB[z * QS + 512 + i]  = bk[z * DD + i];
            qkvB[z * QS + 1024 + i] = bv[z * DD + i];
        }
        return;
    }
    const float* src; ushort* dst;
    int R, C, z, bx, by;
    if (bid < 6144) {              // squares: 4 weights x 6 layers x 16x16 tiles
        int w = bid / 1536, r = bid % 1536;
        z = r / 256; int tl = r % 256; bx = tl % 16; by = tl / 16;
        R = 512; C = 512;
        src = (w == 0) ? Wq : (w == 1) ? Wk : (w == 2) ? Wv : Wo;
        dst = (w < 3) ? (qkvT + (size_t)w * 512 * DD + (size_t)z * QS * DD)
                      : (WoT + (size_t)z * DD * DD);
    } else if (bid < 12288) {      // W1 [512][2048] -> [2048][512]
        int r = bid - 6144;
        z = r / 1024; int tl = r % 1024; bx = tl % 64; by = tl / 64;
        R = 512; C = 2048;
        src = W1; dst = W1T + (size_t)z * 2048 * DD;
    } else {                       // W2 [2048][512] -> [512][2048]
        int r = bid - 12288;
        z = r / 1024; int tl = r % 1024; bx = tl % 16; by = tl / 16;
        R = 2048; C = 512;
        src = W2; dst = W2T + (size_t)z * 2048 * DD;
    }
    const float* Wz = src + (size_t)z * R * C;
    int c0 = bx * 32, r0 = by * 32;
    int x = threadIdx.x, y = threadIdx.y;         // (32,8)
#pragma unroll
    for (int i = 0; i < 32; i += 8)
        t[y + i][x] = f2bf(Wz[(size_t)(r0 + y + i) * C + c0 + x]);
    __syncthreads();
#pragma unroll
    for (int i = 0; i < 32; i += 8)
        dst[(size_t)(c0 + y + i) * R + r0 + x] = t[x][y + i];
}

// ---------------------------------------------------------------------------
// Embedding + positional encoding (vectorized: float4 emb loads, 2 rows/block).
// ---------------------------------------------------------------------------
__global__ __launch_bounds__(256) void embed_pe(const int* __restrict__ x,
                                                const float* __restrict__ emb,
                                                float* __restrict__ h,
                                                ushort* __restrict__ hb) {
    __shared__ int isI32;
    int tid = threadIdx.x;
    if (tid == 0) isI32 = 0;
    __syncthreads();
    int acc = 0;
    for (int i = tid; i < 2048; i += 256) acc |= x[2 * i + 1];
    if (acc) isI32 = 1;
    __syncthreads();
    int rh = tid >> 7, t = tid & 127;
    int row = blockIdx.x * 2 + rh;
    int tok = isI32 ? x[row] : x[2 * row];
    int s = row & (SS - 1);
    const float4 ev = ((const float4*)(emb + (size_t)tok * DD))[t];
    int c0 = t * 4;
    float e[4] = {ev.x, ev.y, ev.z, ev.w};
    float r[4];
#pragma unroll
    for (int j = 0; j < 4; ++j) {
        int c = c0 + j;
        float freq = __expf(-((float)c) * (9.210340371976184f / 256.f));
        float ang = (float)s * freq;
        float pe = (c & 1) ? cosf(ang) : sinf(ang);
        r[j] = e[j] * 22.62741699796952f + pe;
    }
    float4 vo = {r[0], r[1], r[2], r[3]};
    ((float4*)(h + (size_t)row * DD))[t] = vo;
    union { ushort u[4]; unsigned long long ll; } pk;
#pragma unroll
    for (int j = 0; j < 4; ++j) pk.u[j] = f2bf(r[j]);
    *(unsigned long long*)(hb + (size_t)row * DD + c0) = pk.ll;
}

// ---------------------------------------------------------------------------
// 2-phase pipelined GEMM, templated on MI (BM = MI*32; BN=128, BK=64).
// Double-buffered LDS, one barrier per K-step, XOR-swizzled reads +
// pre-swizzled global source. XCD-bijective swizzle (grid%8==0).
// Split-K 2 optional: ks=0 bias -> Cf/Cb; ks=1 -> Cf2.
// ---------------------------------------------------------------------------
template <int MI>
__global__ __launch_bounds__(256) void gemm_t(const ushort* __restrict__ A,
                                              const ushort* __restrict__ BT,
                                              const float* __restrict__ bias,
                                              float* __restrict__ Cf,
                                              ushort* __restrict__ Cb,
                                              float* __restrict__ Cf2,
                                              int M, int N, int K,
                                              int relu, int splitk) {
    constexpr int NI = 4;
    constexpr int BM = MI * 32;
    __shared__ ushort As[2][BM * 64];
    __shared__ ushort Bs[2][128 * 64];

    int nwg = gridDim.x;
    int raw = blockIdx.x;
    int bs = (raw & 7) * (nwg >> 3) + (raw >> 3);   // XCD co-locate
    int kblocks = nwg / splitk;
    int ks = bs / kblocks;
    int tb = bs - ks * kblocks;
    int Keff = K / splitk;
    int kofs = ks * Keff;

    int nbn = N >> 7;
    int bm = (tb / nbn) * BM;
    int bn = (tb % nbn) << 7;
    int tid = threadIdx.x;
    int lane = tid & 63, w = tid >> 6;
    int lr = lane & 15, lg = lane >> 4;

    // staging: chunk = 8 rows x 64 cols = 1KB; lane -> row=lane>>3; global col
    // group pre-swizzled by row&7 so LDS slot s holds global group s^(row&7).
    int srow = lane >> 3;
    int scol = ((lane & 7) ^ srow) * 8;
    const ushort* gA = A + (size_t)(bm + w * (MI * 8) + srow) * K + kofs + scol;
    const ushort* gB = BT + (size_t)(bn + w * 32 + srow) * K + kofs + scol;
    const size_t chG = (size_t)8 * K;

    int wr = (w >> 1) * (MI * 16);
    int wc = (w & 1) * 64;

    int arow[MI], brow[NI];
#pragma unroll
    for (int mi = 0; mi < MI; ++mi) arow[mi] = wr + mi * 16 + lr;
#pragma unroll
    for (int ni = 0; ni < NI; ++ni) brow[ni] = wc + ni * 16 + lr;

    floatx4 acc[MI][NI] = {};
    int T = Keff >> 6;

#pragma unroll
    for (int ch = 0; ch < MI; ++ch)
        stage16(gA + ch * chG, &As[0][(w * (MI * 8) + ch * 8) * 64], lane);
#pragma unroll
    for (int ch = 0; ch < 4; ++ch)
        stage16(gB + ch * chG, &Bs[0][(w * 32 + ch * 8) * 64], lane);
    __syncthreads();

    for (int t = 0; t < T; ++t) {
        int cur = t & 1;
        if (t + 1 < T) {
            int ko = (t + 1) * 64;
#pragma unroll
            for (int ch = 0; ch < MI; ++ch)
                stage16(gA + ch * chG + ko, &As[cur ^ 1][(w * (MI * 8) + ch * 8) * 64], lane);
#pragma unroll
            for (int ch = 0; ch < 4; ++ch)
                stage16(gB + ch * chG + ko, &Bs[cur ^ 1][(w * 32 + ch * 8) * 64], lane);
        }
        short8 af[MI][2], bf[NI][2];
#pragma unroll
        for (int mi = 0; mi < MI; ++mi) {
            int r = arow[mi], sw = (r & 7) * 8;
            af[mi][0] = *(const short8*)&As[cur][r * 64 + ((lg * 8) ^ sw)];
            af[mi][1] = *(const short8*)&As[cur][r * 64 + ((32 + lg * 8) ^ sw)];
        }
#pragma unroll
        for (int ni = 0; ni < NI; ++ni) {
            int r = brow[ni], sw = (r & 7) * 8;
            bf[ni][0] = *(const short8*)&Bs[cur][r * 64 + ((lg * 8) ^ sw)];
            bf[ni][1] = *(const short8*)&Bs[cur][r * 64 + ((32 + lg * 8) ^ sw)];
        }
#pragma unroll
        for (int kh = 0; kh < 2; ++kh)
#pragma unroll
            for (int mi = 0; mi < MI; ++mi)
#pragma unroll
                for (int ni = 0; ni < NI; ++ni)
                    mfma16x16x32(acc[mi][ni], af[mi][kh], bf[ni][kh]);
        if (t + 1 < T) __syncthreads();
    }

#pragma unroll
    for (int ni = 0; ni < NI; ++ni) {
        int col = bn + wc + ni * 16 + lr;
        float bv = ks ? 0.f : bias[col];
#pragma unroll
        for (int mi = 0; mi < MI; ++mi) {
#pragma unroll
            for (int rr = 0; rr < 4; ++rr) {
                int rowi = bm + wr + mi * 16 + lg * 4 + rr;
                float v = acc[mi][ni][rr] + bv;
                if (relu) v = fmaxf(v, 0.f);
                size_t idx = (size_t)rowi * N + col;
                if (ks) { Cf2[idx] = v; }
                else {
                    if (Cf) Cf[idx] = v;
                    if (Cb) Cb[idx] = f2bf(v);
                }
            }
        }
    }
}

// ---------------------------------------------------------------------------
// MFMA flash attention, fused QKV input [4096][1536]. 256 threads = 4 waves,
// wave = 16 q-rows (QBLK=64), KVBLK=128; grid 512 -> 2 blocks/CU so one
// block's barriers overlap the other's compute (R17 isolated occupancy A/B;
// per-wave body identical to R16).
// SWAPPED QK^T: S^T = mfma(K, Q) -> thread (c,g) owns q=c, keys {16t+4g+rr}.
// PV: O^T = mfma(V^T, P^T), key axis permuted by
//   sigma(k) = 32*(t>>1) + 8*g + 4*(t&1) + rr  (t=k>>4, g=(k>>2)&3, rr=k&3)
// applied to BOTH V's LDS position and P's k-index: each thread's B-fragment
// pa_s = [S[2s][0..3], S[2s+1][0..3]] is its OWN registers (no P LDS).
// exp2 softmax, defer-max (THR=11.54), scalar per-thread (mx,dn).
// ---------------------------------------------------------------------------
__global__ __launch_bounds__(256) void attn_mfma(const ushort* __restrict__ QKV,
                                                 ushort* __restrict__ CTX) {
    __shared__ ushort Ks[128][72];
    __shared__ ushort VsT[64][136];   // [dim][sigma(key)]

    int raw = blockIdx.x;
    int bid = (raw & 7) * 64 + (raw >> 3);   // XCD co-locate (grid=512)
    int qt = bid & 31;             // 32 q-tiles of 64 rows
    int hh = (bid >> 5) & 7;
    int bb = bid >> 8;
    int q0 = qt * 64;
    int tid = threadIdx.x;
    int w = tid >> 6, l = tid & 63;
    int c = l & 15, g = l >> 4;

    size_t qbase = (size_t)bb * SS * QS + hh * DHH;
    size_t kbase = qbase + 512;
    size_t vbase = qbase + 1024;
    size_t obase = (size_t)bb * SS * DD + hh * DHH;

    // Q fragments (B operand), scaled by 0.125*log2(e)
    short8 qf[2];
    {
        const ushort* qp = QKV + qbase + (size_t)(q0 + w * 16 + c) * QS + g * 8;
        short8 q0v = *(const short8*)qp;
        short8 q1v = *(const short8*)(qp + 32);
#pragma unroll
        for (int j = 0; j < 8; ++j) {
            q0v[j] = (short)f2bf(bf2f((unsigned short)q0v[j]) * 0.1803368801f);
            q1v[j] = (short)f2bf(bf2f((unsigned short)q1v[j]) * 0.1803368801f);
        }
        qf[0] = q0v; qf[1] = q1v;
    }

    // K prefetch: row kk = tid>>1 (0..127), 32 dims at (tid&1)*32
    int kk = tid >> 1, kd0 = (tid & 1) * 32;
    // V prefetch: key pair kp = 2*(tid&63), 16 dims at (tid>>6)*16
    int kp = (tid & 63) * 2, dv = (tid >> 6) * 16;
    // sigma position for kp (kp and kp+1 adjacent under sigma)
    int t_ = kp >> 4;
    int sp = (t_ >> 1) * 32 + ((kp >> 2) & 3) * 8 + (t_ & 1) * 4 + (kp & 3);

    short8 kreg[4], vreg[4];
    {
        const short8* gk = (const short8*)(QKV + kbase + (size_t)kk * QS + kd0);
        kreg[0] = gk[0]; kreg[1] = gk[1]; kreg[2] = gk[2]; kreg[3] = gk[3];
        const ushort* gv0 = QKV + vbase + (size_t)kp * QS + dv;
        vreg[0] = *(const short8*)gv0;
        vreg[1] = *(const short8*)(gv0 + 8);
        vreg[2] = *(const short8*)(gv0 + QS);
        vreg[3] = *(const short8*)(gv0 + QS + 8);
    }

    floatx4 O[4] = {};           // O[dt][rr] = O[q=c][d=dt*16+4g+rr]
    float mx = -1e30f, dn = 0.f;

    for (int ch = 0; ch < SS; ch += 128) {
        __syncthreads();    // prev chunk's readers done; prefetch loads drained
        *(short8*)&Ks[kk][kd0]      = kreg[0];
        *(short8*)&Ks[kk][kd0 + 8]  = kreg[1];
        *(short8*)&Ks[kk][kd0 + 16] = kreg[2];
        *(short8*)&Ks[kk][kd0 + 24] = kreg[3];
#pragma unroll
        for (int j = 0; j < 8; ++j) {
            unsigned int lo = (unsigned short)vreg[0][j], hi = (unsigned short)vreg[2][j];
            *(unsigned int*)&VsT[dv + j][sp] = lo | (hi << 16);
        }
#pragma unroll
        for (int j = 0; j < 8; ++j) {
            unsigned int lo = (unsigned short)vreg[1][j], hi = (unsigned short)vreg[3][j];
            *(unsigned int*)&VsT[dv + 8 + j][sp] = lo | (hi << 16);
        }
        __syncthreads();    // Ks/VsT ready

        // prefetch next chunk into regs (lands during compute below)
        if (ch + 128 < SS) {
            const short8* gk = (const short8*)(QKV + kbase + (size_t)(ch + 128 + kk) * QS + kd0);
            kreg[0] = gk[0]; kreg[1] = gk[1]; kreg[2] = gk[2]; kreg[3] = gk[3];
            const ushort* gv0 = QKV + vbase + (size_t)(ch + 128 + kp) * QS + dv;
            vreg[0] = *(const short8*)gv0;
            vreg[1] = *(const short8*)(gv0 + 8);
            vreg[2] = *(const short8*)(gv0 + QS);
            vreg[3] = *(const short8*)(gv0 + QS + 8);
        }

        // QK^T swapped: S^T[t] = K_t . Q^T -> col=q(c), row=key(4g+rr)
        floatx4 S[8];
        __builtin_amdgcn_s_setprio(1);
#pragma unroll
        for (int t = 0; t < 8; ++t) {
            floatx4 z = {};
            short8 k0 = *(const short8*)&Ks[t * 16 + c][g * 8];
            short8 k1 = *(const short8*)&Ks[t * 16 + c][32 + g * 8];
            mfma16x16x32(z, k0, qf[0]);
            mfma16x16x32(z, k1, qf[1]);
            S[t] = z;
        }
        __builtin_amdgcn_s_setprio(0);

        // online softmax (exp2 domain), defer-max, scalar mx/dn
        float pml;
        {
            float m0 = fmaxf(fmaxf(S[0][0], S[0][1]), fmaxf(S[0][2], S[0][3]));
            float m1 = fmaxf(fmaxf(S[1][0], S[1][1]), fmaxf(S[1][2], S[1][3]));
            float m2 = fmaxf(fmaxf(S[2][0], S[2][1]), fmaxf(S[2][2], S[2][3]));
            float m3 = fmaxf(fmaxf(S[3][0], S[3][1]), fmaxf(S[3][2], S[3][3]));
            float m4 = fmaxf(fmaxf(S[4][0], S[4][1]), fmaxf(S[4][2], S[4][3]));
            float m5 = fmaxf(fmaxf(S[5][0], S[5][1]), fmaxf(S[5][2], S[5][3]));
            float m6 = fmaxf(fmaxf(S[6][0], S[6][1]), fmaxf(S[6][2], S[6][3]));
            float m7 = fmaxf(fmaxf(S[7][0], S[7][1]), fmaxf(S[7][2], S[7][3]));
            pml = fmaxf(fmaxf(fmaxf(m0, m1), fmaxf(m2, m3)),
                        fmaxf(fmaxf(m4, m5), fmaxf(m6, m7)));
        }
        if (!__all(pml - mx <= 11.54f)) {
            float pm = pml;
            pm = fmaxf(pm, __shfl_xor(pm, 16));   // reduce across g-lanes (same q)
            pm = fmaxf(pm, __shfl_xor(pm, 32));
            float nmr = fmaxf(mx, pm);
            float scr = EXP2F(mx - nmr);
            dn *= scr;
#pragma unroll
            for (int dt = 0; dt < 4; ++dt) {
                O[dt][0] *= scr; O[dt][1] *= scr; O[dt][2] *= scr; O[dt][3] *= scr;
            }
            mx = nmr;
        }
        float ps = 0.f;
#pragma unroll
        for (int t = 0; t < 8; ++t) {
#pragma unroll
            for (int rr = 0; rr < 4; ++rr) {
                S[t][rr] = EXP2F(S[t][rr] - mx);
                ps += S[t][rr];
            }
        }
        dn += ps;

        // PV: O^T += V^T(sigma) . P^T(sigma) — pa built from own registers
        __builtin_amdgcn_s_setprio(1);
#pragma unroll
        for (int s = 0; s < 4; ++s) {
            union { unsigned int u[4]; short8 s8; } pa;
            pa.u[0] = (unsigned int)f2bf_fast(S[2 * s][0]) |
                      ((unsigned int)f2bf_fast(S[2 * s][1]) << 16);
            pa.u[1] = (unsigned int)f2bf_fast(S[2 * s][2]) |
                      ((unsigned int)f2bf_fast(S[2 * s][3]) << 16);
            pa.u[2] = (unsigned int)f2bf_fast(S[2 * s + 1][0]) |
                      ((unsigned int)f2bf_fast(S[2 * s + 1][1]) << 16);
            pa.u[3] = (unsigned int)f2bf_fast(S[2 * s + 1][2]) |
                      ((unsigned int)f2bf_fast(S[2 * s + 1][3]) << 16);
#pragma unroll
            for (int dt = 0; dt < 4; ++dt) {
                short8 vb = *(const short8*)&VsT[dt * 16 + c][s * 32 + g * 8];
                mfma16x16x32(O[dt], vb, pa.s8);
            }
        }
        __builtin_amdgcn_s_setprio(0);
    }

    // epilogue: full denominator across g-lanes, normalize, packed u64 stores
    dn += __shfl_xor(dn, 16);
    dn += __shfl_xor(dn, 32);
    float inv = 1.f / dn;
    size_t orow = obase + (size_t)(q0 + w * 16 + c) * DD;
#pragma unroll
    for (int dt = 0; dt < 4; ++dt) {
        union { ushort u[4]; unsigned long long ll; } pk;
#pragma unroll
        for (int rr = 0; rr < 4; ++rr) pk.u[rr] = f2bf(O[dt][rr] * inv);
        *(unsigned long long*)&CTX[orow + dt * 16 + 4 * g] = pk.ll;
    }
}

// ---------------------------------------------------------------------------
// hout = LayerNorm(hin + yin [+ y2]) * g + b. 256 threads = 2 rows/block,
// float4 loads, single-pass mean/var. Optional bf16 copy.
// ---------------------------------------------------------------------------
__global__ __launch_bounds__(256) void add_ln(const float* __restrict__ hin,
                                              const float* __restrict__ yin,
                                              const float* __restrict__ y2,
                                              const float* __restrict__ g,
                                              const float* __restrict__ b,
                                              float* __restrict__ hout,
                                              ushort* __restrict__ bout) {
    __shared__ float shs[2][2], shq[2][2];
    int rh = threadIdx.x >> 7;          // row half: 0..1
    int t  = threadIdx.x & 127;         // 0..127
    int wv = (threadIdx.x >> 6) & 1;    // wave within row group
    int row = blockIdx.x * 2 + rh;
    const float4 hv = ((const float4*)(hin + (size_t)row * DD))[t];
    const float4 yv = ((const float4*)(yin + (size_t)row * DD))[t];
    float4 v;
    v.x = hv.x + yv.x; v.y = hv.y + yv.y; v.z = hv.z + yv.z; v.w = hv.w + yv.w;
    if (y2) {
        const float4 a = ((const float4*)(y2 + (size_t)row * DD))[t];
        v.x += a.x; v.y += a.y; v.z += a.z; v.w += a.w;
    }
    float s = v.x + v.y + v.z + v.w;
    float q = v.x * v.x + v.y * v.y + v.z * v.z + v.w * v.w;
#pragma unroll
    for (int off = 32; off; off >>= 1) {
        s += __shfl_xor(s, off);
        q += __shfl_xor(q, off);
    }
    if ((threadIdx.x & 63) == 0) { shs[rh][wv] = s; shq[rh][wv] = q; }
    __syncthreads();
    float St = shs[rh][0] + shs[rh][1], Qt = shq[rh][0] + shq[rh][1];
    float mean = St * (1.f / 512.f);
    float var = Qt * (1.f / 512.f) - mean * mean;
    float rstd = rsqrtf(var + 1e-5f);
    const float4 gv = ((const float4*)g)[t];
    const float4 bv = ((const float4*)b)[t];
    float4 r;
    r.x = (v.x - mean) * rstd * gv.x + bv.x;
    r.y = (v.y - mean) * rstd * gv.y + bv.y;
    r.z = (v.z - mean) * rstd * gv.z + bv.z;
    r.w = (v.w - mean) * rstd * gv.w + bv.w;
    ((float4*)(hout + (size_t)row * DD))[t] = r;
    if (bout) {
        union { ushort u[4]; unsigned long long ll; } pk;
        pk.u[0] = f2bf(r.x); pk.u[1] = f2bf(r.y);
        pk.u[2] = f2bf(r.z); pk.u[3] = f2bf(r.w);
        *(unsigned long long*)(bout + (size_t)row * DD + t * 4) = pk.ll;
    }
}

// ---------------------------------------------------------------------------
extern "C" void kernel_launch(void* const* d_in, const int* in_sizes, int n_in,
                              void* d_out, int out_size, void* d_ws, size_t ws_size,
                              hipStream_t stream) {
    const int*   x    = (const int*)d_in[0];
    const float* emb  = (const float*)d_in[1];
    const float* Wq   = (const float*)d_in[2];
    const float* bq   = (const float*)d_in[3];
    const float* Wk   = (const float*)d_in[4];
    const float* bk   = (const float*)d_in[5];
    const float* Wv   = (const float*)d_in[6];
    const float* bv   = (const float*)d_in[7];
    const float* Wo   = (const float*)d_in[8];
    const float* bo   = (const float*)d_in[9];
    const float* W1   = (const float*)d_in[10];
    const float* b1   = (const float*)d_in[11];
    const float* W2   = (const float*)d_in[12];
    const float* b2   = (const float*)d_in[13];
    const float* g1   = (const float*)d_in[14];
    const float* be1  = (const float*)d_in[15];
    const float* g2   = (const float*)d_in[16];
    const float* be2  = (const float*)d_in[17];
    float* out = (float*)d_out;

    char* ws = (char*)d_ws;
    size_t off = 0;
    auto alloc = [&](size_t bytes) -> void* {
        void* p = ws + off;
        off += (bytes + 255) & ~(size_t)255;
        return p;
    };
    float*  h    = (float*)alloc((size_t)NROWS * DD * 4);
    float*  y    = (float*)alloc((size_t)NROWS * DD * 4);
    float*  y2   = (float*)alloc((size_t)NROWS * DD * 4);
    ushort* hb   = (ushort*)alloc((size_t)NROWS * DD * 2);
    ushort* qkv  = (ushort*)alloc((size_t)NROWS * QS * 2);   // 12MB
    ushort* ctxb = (ushort*)alloc((size_t)NROWS * DD * 2);   // 4MB (adjacent)
    ushort* ff1  = qkv;   // FF1 [4096][2048] aliases dead qkv+ctxb (16MB)
    ushort* qkvT = (ushort*)alloc((size_t)6 * QS * DD * 2);
    ushort* WoT  = (ushort*)alloc((size_t)6 * DD * DD * 2);
    ushort* W1T  = (ushort*)alloc((size_t)6 * DD * 2048 * 2);
    ushort* W2T  = (ushort*)alloc((size_t)6 * DD * 2048 * 2);
    float*  qkvB = (float*)alloc((size_t)6 * QS * 4);

    if (ws_size < off) return;   // diagnostic guard (zeros signature)

    prep_weights<<<18438, dim3(32, 8), 0, stream>>>(Wq, Wk, Wv, Wo, W1, W2,
                                                    bq, bk, bv,
                                                    qkvT, WoT, W1T, W2T, qkvB);
    embed_pe<<<2048, 256, 0, stream>>>(x, emb, h, hb);

    for (int l = 0; l < 6; ++l) {
        gemm_t<2><<<768, 256, 0, stream>>>(hb, qkvT + (size_t)l * QS * DD, qkvB + l * QS,
                                           nullptr, qkv, nullptr, NROWS, QS, 512, 0, 1);
        attn_mfma<<<512, 256, 0, stream>>>(qkv, ctxb);
        gemm_t<2><<<256, 256, 0, stream>>>(ctxb, WoT + (size_t)l * DD * DD, bo + l * DD,
                                           y, nullptr, nullptr, NROWS, DD, 512, 0, 1);
        add_ln<<<2048, 256, 0, stream>>>(h, y, nullptr, g1 + l * DD, be1 + l * DD, h, hb);
        gemm_t<4><<<512, 256, 0, stream>>>(hb, W1T + (size_t)l * 2048 * DD, b1 + l * 2048,
                                           nullptr, ff1, nullptr, NROWS, 2048, 512, 1, 1);
        gemm_t<4><<<256, 256, 0, stream>>>(ff1, W2T + (size_t)l * 2048 * DD, b2 + l * DD,
                                           y, nullptr, y2, NROWS, DD, 2048, 0, 2);
        add_ln<<<2048, 256, 0, stream>>>(h, y, y2, g2 + l * DD, be2 + l * DD,
                                         (l == 5) ? out : h, (l == 5) ? nullptr : hb);
    }
}

// Round 18
// 692.621 us; speedup vs baseline: 1.0785x; 1.0785x over previous
//
#include <hip/hip_runtime.h>
#include <hip/hip_bf16.h>

// ---------------------------------------------------------------------------
// TransformerEncoder: B=2, S=2048, D=512, H=8, DH=64, DF=2048, NX=6 layers
// I/O fp32. bf16 MFMA GEMMs (templated BM; BK=64, XOR-swizzled LDS +
// pre-swizzled global_load_lds source, 2-phase dbuf, XCD swizzle).
// QKV: BM=64 grid 768 (3/CU). Wo: BM=64 splitk=1. FF1: BM=128. FF2: BM=128
// splitk=2 (K=2048 regime). Attention: 8-wave QBLK=128 grid 256 (A/B-verified
// optimum), swapped QK^T + sigma-permuted in-register P, exp2 softmax,
// defer-max. Fused weight+bias prep, fp32 LN.  (R18 = revert to R16 best.)
// ---------------------------------------------------------------------------

typedef __attribute__((ext_vector_type(4))) float  floatx4;
typedef __attribute__((ext_vector_type(8))) short  short8;
typedef __bf16 bf16x8 __attribute__((ext_vector_type(8)));

#define SS 2048
#define DD 512
#define HH 8
#define DHH 64
#define NROWS 4096   /* B*S */
#define QS 1536      /* fused qkv row stride */

__device__ __forceinline__ float bf2f(unsigned short u) {
    union { float f; unsigned int i; } x; x.i = ((unsigned int)u) << 16; return x.f;
}
__device__ __forceinline__ unsigned short f2bf(float f) {
    union { float f; unsigned int i; } x; x.f = f;
    unsigned int lsb = (x.i >> 16) & 1u;
    x.i += 0x7fffu + lsb;
    return (unsigned short)(x.i >> 16);
}
// round-half-up for positive finite values (softmax P)
__device__ __forceinline__ unsigned short f2bf_fast(float f) {
    union { float f; unsigned int i; } x; x.f = f;
    return (unsigned short)((x.i + 0x8000u) >> 16);
}

#if __has_builtin(__builtin_amdgcn_exp2f)
#define EXP2F(x) __builtin_amdgcn_exp2f(x)
#else
#define EXP2F(x) exp2f(x)
#endif

#if __has_builtin(__builtin_amdgcn_mfma_f32_16x16x32_bf16)
__device__ __forceinline__ void mfma16x16x32(floatx4& d, short8 a, short8 b) {
    bf16x8 ab, bb;
    __builtin_memcpy(&ab, &a, 16);
    __builtin_memcpy(&bb, &b, 16);
    d = __builtin_amdgcn_mfma_f32_16x16x32_bf16(ab, bb, d, 0, 0, 0);
}
#else
__device__ __forceinline__ void mfma16x16x32(floatx4& d, short8 a, short8 b) {
    asm volatile("s_nop 1\n\t"
                 "v_mfma_f32_16x16x32_bf16 %0, %1, %2, %0\n\t"
                 "s_nop 7\n\t"
                 "s_nop 7"
                 : "+v"(d) : "v"(a), "v"(b));
}
#endif

// stage 16B/lane: g = per-lane global src, lbase = wave-uniform LDS chunk base
#if __has_builtin(__builtin_amdgcn_global_load_lds)
__device__ __forceinline__ void stage16(const ushort* g, ushort* lbase, int lane) {
    __builtin_amdgcn_global_load_lds(
        (const __attribute__((address_space(1))) unsigned int*)g,
        (__attribute__((address_space(3))) unsigned int*)lbase, 16, 0, 0);
}
#else
__device__ __forceinline__ void stage16(const ushort* g, ushort* lbase, int lane) {
    *(short8*)(lbase + lane * 8) = *(const short8*)g;
}
#endif

// ---------------------------------------------------------------------------
// All weight transposes (fp32 -> bf16, [z][R][C] -> [C][R]) + qkv bias concat
// in ONE kernel. Blocks 0..18431: transpose tiles; 18432..18437: bias concat.
// ---------------------------------------------------------------------------
__global__ __launch_bounds__(256) void prep_weights(const float* __restrict__ Wq,
                                                    const float* __restrict__ Wk,
                                                    const float* __restrict__ Wv,
                                                    const float* __restrict__ Wo,
                                                    const float* __restrict__ W1,
                                                    const float* __restrict__ W2,
                                                    const float* __restrict__ bq,
                                                    const float* __restrict__ bk,
                                                    const float* __restrict__ bv,
                                                    ushort* __restrict__ qkvT,
                                                    ushort* __restrict__ WoT,
                                                    ushort* __restrict__ W1T,
                                                    ushort* __restrict__ W2T,
                                                    float* __restrict__ qkvB) {
    __shared__ ushort t[32][33];
    int bid = blockIdx.x;
    if (bid >= 18432) {            // bias concat: one block per layer
        int z = bid - 18432;
        int idx = threadIdx.y * 32 + threadIdx.x;
        for (int i = idx; i < 512; i += 256) {
            qkvB[z * QS + i]        = bq[z * DD + i];
            qkvB[z * QS + 512 + i]  = bk[z * DD + i];
            qkvB[z * QS + 1024 + i] = bv[z * DD + i];
        }
        return;
    }
    const float* src; ushort* dst;
    int R, C, z, bx, by;
    if (bid < 6144) {              // squares: 4 weights x 6 layers x 16x16 tiles
        int w = bid / 1536, r = bid % 1536;
        z = r / 256; int tl = r % 256; bx = tl % 16; by = tl / 16;
        R = 512; C = 512;
        src = (w == 0) ? Wq : (w == 1) ? Wk : (w == 2) ? Wv : Wo;
        dst = (w < 3) ? (qkvT + (size_t)w * 512 * DD + (size_t)z * QS * DD)
                      : (WoT + (size_t)z * DD * DD);
    } else if (bid < 12288) {      // W1 [512][2048] -> [2048][512]
        int r = bid - 6144;
        z = r / 1024; int tl = r % 1024; bx = tl % 64; by = tl / 64;
        R = 512; C = 2048;
        src = W1; dst = W1T + (size_t)z * 2048 * DD;
    } else {                       // W2 [2048][512] -> [512][2048]
        int r = bid - 12288;
        z = r / 1024; int tl = r % 1024; bx = tl % 16; by = tl / 16;
        R = 2048; C = 512;
        src = W2; dst = W2T + (size_t)z * 2048 * DD;
    }
    const float* Wz = src + (size_t)z * R * C;
    int c0 = bx * 32, r0 = by * 32;
    int x = threadIdx.x, y = threadIdx.y;         // (32,8)
#pragma unroll
    for (int i = 0; i < 32; i += 8)
        t[y + i][x] = f2bf(Wz[(size_t)(r0 + y + i) * C + c0 + x]);
    __syncthreads();
#pragma unroll
    for (int i = 0; i < 32; i += 8)
        dst[(size_t)(c0 + y + i) * R + r0 + x] = t[x][y + i];
}

// ---------------------------------------------------------------------------
// Embedding + positional encoding (vectorized: float4 emb loads, 2 rows/block).
// ---------------------------------------------------------------------------
__global__ __launch_bounds__(256) void embed_pe(const int* __restrict__ x,
                                                const float* __restrict__ emb,
                                                float* __restrict__ h,
                                                ushort* __restrict__ hb) {
    __shared__ int isI32;
    int tid = threadIdx.x;
    if (tid == 0) isI32 = 0;
    __syncthreads();
    int acc = 0;
    for (int i = tid; i < 2048; i += 256) acc |= x[2 * i + 1];
    if (acc) isI32 = 1;
    __syncthreads();
    int rh = tid >> 7, t = tid & 127;
    int row = blockIdx.x * 2 + rh;
    int tok = isI32 ? x[row] : x[2 * row];
    int s = row & (SS - 1);
    const float4 ev = ((const float4*)(emb + (size_t)tok * DD))[t];
    int c0 = t * 4;
    float e[4] = {ev.x, ev.y, ev.z, ev.w};
    float r[4];
#pragma unroll
    for (int j = 0; j < 4; ++j) {
        int c = c0 + j;
        float freq = __expf(-((float)c) * (9.210340371976184f / 256.f));
        float ang = (float)s * freq;
        float pe = (c & 1) ? cosf(ang) : sinf(ang);
        r[j] = e[j] * 22.62741699796952f + pe;
    }
    float4 vo = {r[0], r[1], r[2], r[3]};
    ((float4*)(h + (size_t)row * DD))[t] = vo;
    union { ushort u[4]; unsigned long long ll; } pk;
#pragma unroll
    for (int j = 0; j < 4; ++j) pk.u[j] = f2bf(r[j]);
    *(unsigned long long*)(hb + (size_t)row * DD + c0) = pk.ll;
}

// ---------------------------------------------------------------------------
// 2-phase pipelined GEMM, templated on MI (BM = MI*32; BN=128, BK=64).
// Double-buffered LDS, one barrier per K-step, XOR-swizzled reads +
// pre-swizzled global source. XCD-bijective swizzle (grid%8==0).
// Split-K 2 optional: ks=0 bias -> Cf/Cb; ks=1 -> Cf2.
// ---------------------------------------------------------------------------
template <int MI>
__global__ __launch_bounds__(256) void gemm_t(const ushort* __restrict__ A,
                                              const ushort* __restrict__ BT,
                                              const float* __restrict__ bias,
                                              float* __restrict__ Cf,
                                              ushort* __restrict__ Cb,
                                              float* __restrict__ Cf2,
                                              int M, int N, int K,
                                              int relu, int splitk) {
    constexpr int NI = 4;
    constexpr int BM = MI * 32;
    __shared__ ushort As[2][BM * 64];
    __shared__ ushort Bs[2][128 * 64];

    int nwg = gridDim.x;
    int raw = blockIdx.x;
    int bs = (raw & 7) * (nwg >> 3) + (raw >> 3);   // XCD co-locate
    int kblocks = nwg / splitk;
    int ks = bs / kblocks;
    int tb = bs - ks * kblocks;
    int Keff = K / splitk;
    int kofs = ks * Keff;

    int nbn = N >> 7;
    int bm = (tb / nbn) * BM;
    int bn = (tb % nbn) << 7;
    int tid = threadIdx.x;
    int lane = tid & 63, w = tid >> 6;
    int lr = lane & 15, lg = lane >> 4;

    // staging: chunk = 8 rows x 64 cols = 1KB; lane -> row=lane>>3; global col
    // group pre-swizzled by row&7 so LDS slot s holds global group s^(row&7).
    int srow = lane >> 3;
    int scol = ((lane & 7) ^ srow) * 8;
    const ushort* gA = A + (size_t)(bm + w * (MI * 8) + srow) * K + kofs + scol;
    const ushort* gB = BT + (size_t)(bn + w * 32 + srow) * K + kofs + scol;
    const size_t chG = (size_t)8 * K;

    int wr = (w >> 1) * (MI * 16);
    int wc = (w & 1) * 64;

    int arow[MI], brow[NI];
#pragma unroll
    for (int mi = 0; mi < MI; ++mi) arow[mi] = wr + mi * 16 + lr;
#pragma unroll
    for (int ni = 0; ni < NI; ++ni) brow[ni] = wc + ni * 16 + lr;

    floatx4 acc[MI][NI] = {};
    int T = Keff >> 6;

#pragma unroll
    for (int ch = 0; ch < MI; ++ch)
        stage16(gA + ch * chG, &As[0][(w * (MI * 8) + ch * 8) * 64], lane);
#pragma unroll
    for (int ch = 0; ch < 4; ++ch)
        stage16(gB + ch * chG, &Bs[0][(w * 32 + ch * 8) * 64], lane);
    __syncthreads();

    for (int t = 0; t < T; ++t) {
        int cur = t & 1;
        if (t + 1 < T) {
            int ko = (t + 1) * 64;
#pragma unroll
            for (int ch = 0; ch < MI; ++ch)
                stage16(gA + ch * chG + ko, &As[cur ^ 1][(w * (MI * 8) + ch * 8) * 64], lane);
#pragma unroll
            for (int ch = 0; ch < 4; ++ch)
                stage16(gB + ch * chG + ko, &Bs[cur ^ 1][(w * 32 + ch * 8) * 64], lane);
        }
        short8 af[MI][2], bf[NI][2];
#pragma unroll
        for (int mi = 0; mi < MI; ++mi) {
            int r = arow[mi], sw = (r & 7) * 8;
            af[mi][0] = *(const short8*)&As[cur][r * 64 + ((lg * 8) ^ sw)];
            af[mi][1] = *(const short8*)&As[cur][r * 64 + ((32 + lg * 8) ^ sw)];
        }
#pragma unroll
        for (int ni = 0; ni < NI; ++ni) {
            int r = brow[ni], sw = (r & 7) * 8;
            bf[ni][0] = *(const short8*)&Bs[cur][r * 64 + ((lg * 8) ^ sw)];
            bf[ni][1] = *(const short8*)&Bs[cur][r * 64 + ((32 + lg * 8) ^ sw)];
        }
#pragma unroll
        for (int kh = 0; kh < 2; ++kh)
#pragma unroll
            for (int mi = 0; mi < MI; ++mi)
#pragma unroll
                for (int ni = 0; ni < NI; ++ni)
                    mfma16x16x32(acc[mi][ni], af[mi][kh], bf[ni][kh]);
        if (t + 1 < T) __syncthreads();
    }

#pragma unroll
    for (int ni = 0; ni < NI; ++ni) {
        int col = bn + wc + ni * 16 + lr;
        float bv = ks ? 0.f : bias[col];
#pragma unroll
        for (int mi = 0; mi < MI; ++mi) {
#pragma unroll
            for (int rr = 0; rr < 4; ++rr) {
                int rowi = bm + wr + mi * 16 + lg * 4 + rr;
                float v = acc[mi][ni][rr] + bv;
                if (relu) v = fmaxf(v, 0.f);
                size_t idx = (size_t)rowi * N + col;
                if (ks) { Cf2[idx] = v; }
                else {
                    if (Cf) Cf[idx] = v;
                    if (Cb) Cb[idx] = f2bf(v);
                }
            }
        }
    }
}

// ---------------------------------------------------------------------------
// MFMA flash attention (A/B-verified optimum config), fused QKV [4096][1536].
// 512 threads = 8 waves, wave = 16 q-rows (QBLK=128), KVBLK=128, grid 256.
// SWAPPED QK^T: S^T = mfma(K, Q) -> thread (c,g) owns q=c, keys {16t+4g+rr}.
// PV: O^T = mfma(V^T, P^T), key axis permuted by
//   sigma(k) = 32*(t>>1) + 8*g + 4*(t&1) + rr  (t=k>>4, g=(k>>2)&3, rr=k&3)
// applied to BOTH V's LDS position and P's k-index: each thread's B-fragment
// pa_s = [S[2s][0..3], S[2s+1][0..3]] is its OWN registers (no P LDS).
// exp2 softmax, defer-max (THR=11.54), scalar per-thread (mx,dn).
// ---------------------------------------------------------------------------
__global__ __launch_bounds__(512) void attn_mfma(const ushort* __restrict__ QKV,
                                                 ushort* __restrict__ CTX) {
    __shared__ ushort Ks[128][72];
    __shared__ ushort VsT[64][136];   // [dim][sigma(key)]

    int raw = blockIdx.x;
    int bid = (raw & 7) * 32 + (raw >> 3);   // XCD co-locate (grid=256)
    int qt = bid & 15;             // 16 q-tiles of 128 rows
    int hh = (bid >> 4) & 7;
    int bb = bid >> 7;
    int q0 = qt * 128;
    int tid = threadIdx.x;
    int w = tid >> 6, l = tid & 63;
    int c = l & 15, g = l >> 4;

    size_t qbase = (size_t)bb * SS * QS + hh * DHH;
    size_t kbase = qbase + 512;
    size_t vbase = qbase + 1024;
    size_t obase = (size_t)bb * SS * DD + hh * DHH;

    // Q fragments (B operand), scaled by 0.125*log2(e)
    short8 qf[2];
    {
        const ushort* qp = QKV + qbase + (size_t)(q0 + w * 16 + c) * QS + g * 8;
        short8 q0v = *(const short8*)qp;
        short8 q1v = *(const short8*)(qp + 32);
#pragma unroll
        for (int j = 0; j < 8; ++j) {
            q0v[j] = (short)f2bf(bf2f((unsigned short)q0v[j]) * 0.1803368801f);
            q1v[j] = (short)f2bf(bf2f((unsigned short)q1v[j]) * 0.1803368801f);
        }
        qf[0] = q0v; qf[1] = q1v;
    }

    // K prefetch: row kk = tid>>2 (0..127), 16 dims at (tid&3)*16
    int kk = tid >> 2, kd0 = (tid & 3) * 16;
    // V prefetch: key pair kp = 2*(tid&63), 8 dims at (tid>>6)*8
    int kp = (tid & 63) * 2, dv = (tid >> 6) * 8;
    // sigma position for kp (kp and kp+1 adjacent under sigma)
    int t_ = kp >> 4;
    int sp = (t_ >> 1) * 32 + ((kp >> 2) & 3) * 8 + (t_ & 1) * 4 + (kp & 3);

    short8 kreg[2], vreg[2];
    {
        const short8* gk = (const short8*)(QKV + kbase + (size_t)kk * QS + kd0);
        kreg[0] = gk[0]; kreg[1] = gk[1];
        vreg[0] = *(const short8*)(QKV + vbase + (size_t)kp * QS + dv);
        vreg[1] = *(const short8*)(QKV + vbase + (size_t)(kp + 1) * QS + dv);
    }

    floatx4 O[4] = {};           // O[dt][rr] = O[q=c][d=dt*16+4g+rr]
    float mx = -1e30f, dn = 0.f;

    for (int ch = 0; ch < SS; ch += 128) {
        __syncthreads();    // prev chunk's readers done; prefetch loads drained
        *(short8*)&Ks[kk][kd0]     = kreg[0];
        *(short8*)&Ks[kk][kd0 + 8] = kreg[1];
#pragma unroll
        for (int j = 0; j < 8; ++j) {
            unsigned int lo = (unsigned short)vreg[0][j], hi = (unsigned short)vreg[1][j];
            *(unsigned int*)&VsT[dv + j][sp] = lo | (hi << 16);
        }
        __syncthreads();    // Ks/VsT ready

        // prefetch next chunk into regs (lands during compute below)
        if (ch + 128 < SS) {
            const short8* gk = (const short8*)(QKV + kbase + (size_t)(ch + 128 + kk) * QS + kd0);
            kreg[0] = gk[0]; kreg[1] = gk[1];
            vreg[0] = *(const short8*)(QKV + vbase + (size_t)(ch + 128 + kp) * QS + dv);
            vreg[1] = *(const short8*)(QKV + vbase + (size_t)(ch + 128 + kp + 1) * QS + dv);
        }

        // QK^T swapped: S^T[t] = K_t . Q^T -> col=q(c), row=key(4g+rr)
        floatx4 S[8];
        __builtin_amdgcn_s_setprio(1);
#pragma unroll
        for (int t = 0; t < 8; ++t) {
            floatx4 z = {};
            short8 k0 = *(const short8*)&Ks[t * 16 + c][g * 8];
            short8 k1 = *(const short8*)&Ks[t * 16 + c][32 + g * 8];
            mfma16x16x32(z, k0, qf[0]);
            mfma16x16x32(z, k1, qf[1]);
            S[t] = z;
        }
        __builtin_amdgcn_s_setprio(0);

        // online softmax (exp2 domain), defer-max, scalar mx/dn
        float pml;
        {
            float m0 = fmaxf(fmaxf(S[0][0], S[0][1]), fmaxf(S[0][2], S[0][3]));
            float m1 = fmaxf(fmaxf(S[1][0], S[1][1]), fmaxf(S[1][2], S[1][3]));
            float m2 = fmaxf(fmaxf(S[2][0], S[2][1]), fmaxf(S[2][2], S[2][3]));
            float m3 = fmaxf(fmaxf(S[3][0], S[3][1]), fmaxf(S[3][2], S[3][3]));
            float m4 = fmaxf(fmaxf(S[4][0], S[4][1]), fmaxf(S[4][2], S[4][3]));
            float m5 = fmaxf(fmaxf(S[5][0], S[5][1]), fmaxf(S[5][2], S[5][3]));
            float m6 = fmaxf(fmaxf(S[6][0], S[6][1]), fmaxf(S[6][2], S[6][3]));
            float m7 = fmaxf(fmaxf(S[7][0], S[7][1]), fmaxf(S[7][2], S[7][3]));
            pml = fmaxf(fmaxf(fmaxf(m0, m1), fmaxf(m2, m3)),
                        fmaxf(fmaxf(m4, m5), fmaxf(m6, m7)));
        }
        if (!__all(pml - mx <= 11.54f)) {
            float pm = pml;
            pm = fmaxf(pm, __shfl_xor(pm, 16));   // reduce across g-lanes (same q)
            pm = fmaxf(pm, __shfl_xor(pm, 32));
            float nmr = fmaxf(mx, pm);
            float scr = EXP2F(mx - nmr);
            dn *= scr;
#pragma unroll
            for (int dt = 0; dt < 4; ++dt) {
                O[dt][0] *= scr; O[dt][1] *= scr; O[dt][2] *= scr; O[dt][3] *= scr;
            }
            mx = nmr;
        }
        float ps = 0.f;
#pragma unroll
        for (int t = 0; t < 8; ++t) {
#pragma unroll
            for (int rr = 0; rr < 4; ++rr) {
                S[t][rr] = EXP2F(S[t][rr] - mx);
                ps += S[t][rr];
            }
        }
        dn += ps;

        // PV: O^T += V^T(sigma) . P^T(sigma) — pa built from own registers
        __builtin_amdgcn_s_setprio(1);
#pragma unroll
        for (int s = 0; s < 4; ++s) {
            union { unsigned int u[4]; short8 s8; } pa;
            pa.u[0] = (unsigned int)f2bf_fast(S[2 * s][0]) |
                      ((unsigned int)f2bf_fast(S[2 * s][1]) << 16);
            pa.u[1] = (unsigned int)f2bf_fast(S[2 * s][2]) |
                      ((unsigned int)f2bf_fast(S[2 * s][3]) << 16);
            pa.u[2] = (unsigned int)f2bf_fast(S[2 * s + 1][0]) |
                      ((unsigned int)f2bf_fast(S[2 * s + 1][1]) << 16);
            pa.u[3] = (unsigned int)f2bf_fast(S[2 * s + 1][2]) |
                      ((unsigned int)f2bf_fast(S[2 * s + 1][3]) << 16);
#pragma unroll
            for (int dt = 0; dt < 4; ++dt) {
                short8 vb = *(const short8*)&VsT[dt * 16 + c][s * 32 + g * 8];
                mfma16x16x32(O[dt], vb, pa.s8);
            }
        }
        __builtin_amdgcn_s_setprio(0);
    }

    // epilogue: full denominator across g-lanes, normalize, packed u64 stores
    dn += __shfl_xor(dn, 16);
    dn += __shfl_xor(dn, 32);
    float inv = 1.f / dn;
    size_t orow = obase + (size_t)(q0 + w * 16 + c) * DD;
#pragma unroll
    for (int dt = 0; dt < 4; ++dt) {
        union { ushort u[4]; unsigned long long ll; } pk;
#pragma unroll
        for (int rr = 0; rr < 4; ++rr) pk.u[rr] = f2bf(O[dt][rr] * inv);
        *(unsigned long long*)&CTX[orow + dt * 16 + 4 * g] = pk.ll;
    }
}

// ---------------------------------------------------------------------------
// hout = LayerNorm(hin + yin [+ y2]) * g + b. 256 threads = 2 rows/block,
// float4 loads, single-pass mean/var. Optional bf16 copy.
// ---------------------------------------------------------------------------
__global__ __launch_bounds__(256) void add_ln(const float* __restrict__ hin,
                                              const float* __restrict__ yin,
                                              const float* __restrict__ y2,
                                              const float* __restrict__ g,
                                              const float* __restrict__ b,
                                              float* __restrict__ hout,
                                              ushort* __restrict__ bout) {
    __shared__ float shs[2][2], shq[2][2];
    int rh = threadIdx.x >> 7;          // row half: 0..1
    int t  = threadIdx.x & 127;         // 0..127
    int wv = (threadIdx.x >> 6) & 1;    // wave within row group
    int row = blockIdx.x * 2 + rh;
    const float4 hv = ((const float4*)(hin + (size_t)row * DD))[t];
    const float4 yv = ((const float4*)(yin + (size_t)row * DD))[t];
    float4 v;
    v.x = hv.x + yv.x; v.y = hv.y + yv.y; v.z = hv.z + yv.z; v.w = hv.w + yv.w;
    if (y2) {
        const float4 a = ((const float4*)(y2 + (size_t)row * DD))[t];
        v.x += a.x; v.y += a.y; v.z += a.z; v.w += a.w;
    }
    float s = v.x + v.y + v.z + v.w;
    float q = v.x * v.x + v.y * v.y + v.z * v.z + v.w * v.w;
#pragma unroll
    for (int off = 32; off; off >>= 1) {
        s += __shfl_xor(s, off);
        q += __shfl_xor(q, off);
    }
    if ((threadIdx.x & 63) == 0) { shs[rh][wv] = s; shq[rh][wv] = q; }
    __syncthreads();
    float St = shs[rh][0] + shs[rh][1], Qt = shq[rh][0] + shq[rh][1];
    float mean = St * (1.f / 512.f);
    float var = Qt * (1.f / 512.f) - mean * mean;
    float rstd = rsqrtf(var + 1e-5f);
    const float4 gv = ((const float4*)g)[t];
    const float4 bv = ((const float4*)b)[t];
    float4 r;
    r.x = (v.x - mean) * rstd * gv.x + bv.x;
    r.y = (v.y - mean) * rstd * gv.y + bv.y;
    r.z = (v.z - mean) * rstd * gv.z + bv.z;
    r.w = (v.w - mean) * rstd * gv.w + bv.w;
    ((float4*)(hout + (size_t)row * DD))[t] = r;
    if (bout) {
        union { ushort u[4]; unsigned long long ll; } pk;
        pk.u[0] = f2bf(r.x); pk.u[1] = f2bf(r.y);
        pk.u[2] = f2bf(r.z); pk.u[3] = f2bf(r.w);
        *(unsigned long long*)(bout + (size_t)row * DD + t * 4) = pk.ll;
    }
}

// ---------------------------------------------------------------------------
extern "C" void kernel_launch(void* const* d_in, const int* in_sizes, int n_in,
                              void* d_out, int out_size, void* d_ws, size_t ws_size,
                              hipStream_t stream) {
    const int*   x    = (const int*)d_in[0];
    const float* emb  = (const float*)d_in[1];
    const float* Wq   = (const float*)d_in[2];
    const float* bq   = (const float*)d_in[3];
    const float* Wk   = (const float*)d_in[4];
    const float* bk   = (const float*)d_in[5];
    const float* Wv   = (const float*)d_in[6];
    const float* bv   = (const float*)d_in[7];
    const float* Wo   = (const float*)d_in[8];
    const float* bo   = (const float*)d_in[9];
    const float* W1   = (const float*)d_in[10];
    const float* b1   = (const float*)d_in[11];
    const float* W2   = (const float*)d_in[12];
    const float* b2   = (const float*)d_in[13];
    const float* g1   = (const float*)d_in[14];
    const float* be1  = (const float*)d_in[15];
    const float* g2   = (const float*)d_in[16];
    const float* be2  = (const float*)d_in[17];
    float* out = (float*)d_out;

    char* ws = (char*)d_ws;
    size_t off = 0;
    auto alloc = [&](size_t bytes) -> void* {
        void* p = ws + off;
        off += (bytes + 255) & ~(size_t)255;
        return p;
    };
    float*  h    = (float*)alloc((size_t)NROWS * DD * 4);
    float*  y    = (float*)alloc((size_t)NROWS * DD * 4);
    float*  y2   = (float*)alloc((size_t)NROWS * DD * 4);
    ushort* hb   = (ushort*)alloc((size_t)NROWS * DD * 2);
    ushort* qkv  = (ushort*)alloc((size_t)NROWS * QS * 2);   // 12MB
    ushort* ctxb = (ushort*)alloc((size_t)NROWS * DD * 2);   // 4MB (adjacent)
    ushort* ff1  = qkv;   // FF1 [4096][2048] aliases dead qkv+ctxb (16MB)
    ushort* qkvT = (ushort*)alloc((size_t)6 * QS * DD * 2);
    ushort* WoT  = (ushort*)alloc((size_t)6 * DD * DD * 2);
    ushort* W1T  = (ushort*)alloc((size_t)6 * DD * 2048 * 2);
    ushort* W2T  = (ushort*)alloc((size_t)6 * DD * 2048 * 2);
    float*  qkvB = (float*)alloc((size_t)6 * QS * 4);

    if (ws_size < off) return;   // diagnostic guard (zeros signature)

    prep_weights<<<18438, dim3(32, 8), 0, stream>>>(Wq, Wk, Wv, Wo, W1, W2,
                                                    bq, bk, bv,
                                                    qkvT, WoT, W1T, W2T, qkvB);
    embed_pe<<<2048, 256, 0, stream>>>(x, emb, h, hb);

    for (int l = 0; l < 6; ++l) {
        gemm_t<2><<<768, 256, 0, stream>>>(hb, qkvT + (size_t)l * QS * DD, qkvB + l * QS,
                                           nullptr, qkv, nullptr, NROWS, QS, 512, 0, 1);
        attn_mfma<<<256, 512, 0, stream>>>(qkv, ctxb);
        gemm_t<2><<<256, 256, 0, stream>>>(ctxb, WoT + (size_t)l * DD * DD, bo + l * DD,
                                           y, nullptr, nullptr, NROWS, DD, 512, 0, 1);
        add_ln<<<2048, 256, 0, stream>>>(h, y, nullptr, g1 + l * DD, be1 + l * DD, h, hb);
        gemm_t<4><<<512, 256, 0, stream>>>(hb, W1T + (size_t)l * 2048 * DD, b1 + l * 2048,
                                           nullptr, ff1, nullptr, NROWS, 2048, 512, 1, 1);
        gemm_t<4><<<256, 256, 0, stream>>>(ff1, W2T + (size_t)l * 2048 * DD, b2 + l * DD,
                                           y, nullptr, y2, NROWS, DD, 2048, 0, 2);
        add_ln<<<2048, 256, 0, stream>>>(h, y, y2, g2 + l * DD, be2 + l * DD,
                                         (l == 5) ? out : h, (l == 5) ? nullptr : hb);
    }
}